// Round 1
// baseline (798.338 us; speedup 1.0000x reference)
//
#include <hip/hip_runtime.h>
#include <math.h>

#define NN    8
#define CC    256
#define HH    128
#define WW    128
#define HWHW  16384
#define NBOX  20

constexpr float C_ALPHA = 1e-3f, C_BETA = 5e-4f, C_GAMMA = 1e-3f, C_LAMB = 5e-6f;
constexpr float C_LN_EPS = 1e-5f;

// ws layout (float offsets)
#define OFF_FEA_S   0          // [N*HW]
#define OFF_FEA_T   131072
#define OFF_CM_S    262144
#define OFF_CM_T    393216
#define OFF_MFG     524288     // [N*HW]
#define OFF_PCHS    655360     // [512*256] per-block partial ch_S
#define OFF_PCHT    786432
#define OFF_PD      917504
#define OFF_PCTXS   1048576
#define OFF_PCTXT   1179648
#define OFF_CHS     1310720    // [2048]
#define OFF_CHT     1312768
#define OFF_DSUM    1314816
#define OFF_CATT    1316864    // C_att for T
#define OFF_CTXS    1318912
#define OFF_CTXT    1320960
#define OFF_STATS   1323008    // [N*8] {mxFS,ZFS,mxFT,ZFT,mxCS,ZCS,mxCT,ZCT}
#define OFF_BG      1323072    // [8] bg pixel counts
#define OFF_SCAL    1323080    // [8] 0: sum(S-T)^2, 1: fg/bg combined, 2: mask loss sum
#define WS_FLOATS   1323088

// ---- wave-64 reductions via DPP (VALU pipe, no LDS traffic) ----
__device__ __forceinline__ float dpp_wave_sum(float x) {
  // total lands in lane 63
#define DPPADD(ctrl, rm) \
  x += __int_as_float(__builtin_amdgcn_update_dpp(0, __float_as_int(x), ctrl, rm, 0xf, true));
  DPPADD(0x111, 0xf)  // row_shr:1
  DPPADD(0x112, 0xf)  // row_shr:2
  DPPADD(0x114, 0xf)  // row_shr:4
  DPPADD(0x118, 0xf)  // row_shr:8
  DPPADD(0x142, 0xa)  // row_bcast:15 -> rows 1,3
  DPPADD(0x143, 0xc)  // row_bcast:31 -> rows 2,3
#undef DPPADD
  return x;
}

__device__ __forceinline__ float dpp_wave_max(float x) {
#define DPPMAX(ctrl, rm) { \
  int r_ = __builtin_amdgcn_update_dpp(__float_as_int(x), __float_as_int(x), ctrl, rm, 0xf, false); \
  x = fmaxf(x, __int_as_float(r_)); }
  DPPMAX(0x111, 0xf)
  DPPMAX(0x112, 0xf)
  DPPMAX(0x114, 0xf)
  DPPMAX(0x118, 0xf)
  DPPMAX(0x142, 0xa)
  DPPMAX(0x143, 0xc)
#undef DPPMAX
  return x;
}

__device__ __forceinline__ float block_sum256(float v, float* sm) {
  int tid = threadIdx.x;
  v = dpp_wave_sum(v);
  if ((tid & 63) == 63) sm[tid >> 6] = v;
  __syncthreads();
  float r = sm[0] + sm[1] + sm[2] + sm[3];
  __syncthreads();
  return r;
}

__device__ __forceinline__ float block_max256(float v, float* sm) {
  int tid = threadIdx.x;
  v = dpp_wave_max(v);
  if ((tid & 63) == 63) sm[tid >> 6] = v;
  __syncthreads();
  float r = fmaxf(fmaxf(sm[0], sm[1]), fmaxf(sm[2], sm[3]));
  __syncthreads();
  return r;
}

// ---- K1: pass 1 over S,T ----
// grid 512 = N * (HW/256); block 256 (thread = pixel), loop over channels
__global__ __launch_bounds__(256) void k1_pass1(
    const float* __restrict__ S, const float* __restrict__ T,
    const float* __restrict__ w_ms, const float* __restrict__ w_mt,
    float* __restrict__ ws) {
  int tid  = threadIdx.x;
  int n    = blockIdx.x >> 6;
  int pix  = ((blockIdx.x & 63) << 8) | tid;
  int lane = tid & 63, wave = tid >> 6;

  __shared__ float l_ws[CC], l_wt[CC];
  __shared__ float l_chS[4][CC], l_chT[4][CC], l_D[4][CC];
  __shared__ float l_sq[4];
  l_ws[tid] = w_ms[tid];
  l_wt[tid] = w_mt[tid];
  __syncthreads();

  const float* ps = S + (size_t)n * CC * HWHW + pix;
  const float* pt = T + (size_t)n * CC * HWHW + pix;

  float feaS = 0.f, feaT = 0.f, cmS = 0.f, cmT = 0.f, sq = 0.f;
#pragma unroll 4
  for (int c = 0; c < CC; c++) {
    float s = ps[c * HWHW], t = pt[c * HWHW];
    float as_ = fabsf(s), at_ = fabsf(t), d = s - t;
    feaS += as_; feaT += at_;
    cmS = fmaf(s, l_ws[c], cmS);
    cmT = fmaf(t, l_wt[c], cmT);
    sq  = fmaf(d, d, sq);
    as_ = dpp_wave_sum(as_);
    at_ = dpp_wave_sum(at_);
    d   = dpp_wave_sum(d);
    if (lane == 63) { l_chS[wave][c] = as_; l_chT[wave][c] = at_; l_D[wave][c] = d; }
  }

  int gp = n * HWHW + pix;
  ws[OFF_FEA_S + gp] = feaS;
  ws[OFF_FEA_T + gp] = feaT;
  ws[OFF_CM_S + gp]  = cmS;   // bias b_ms dropped: softmax shift-invariant
  ws[OFF_CM_T + gp]  = cmT;
  __syncthreads();

  int bo = blockIdx.x * CC + tid;
  ws[OFF_PCHS + bo] = l_chS[0][tid] + l_chS[1][tid] + l_chS[2][tid] + l_chS[3][tid];
  ws[OFF_PCHT + bo] = l_chT[0][tid] + l_chT[1][tid] + l_chT[2][tid] + l_chT[3][tid];
  ws[OFF_PD + bo]   = l_D[0][tid]   + l_D[1][tid]   + l_D[2][tid]   + l_D[3][tid];

  sq = dpp_wave_sum(sq);
  if (lane == 63) l_sq[wave] = sq;
  __syncthreads();
  if (tid == 0) atomicAdd(&ws[OFF_SCAL + 0], l_sq[0] + l_sq[1] + l_sq[2] + l_sq[3]);
}

// ---- K2: foreground mask + bg pixel count ----
__global__ __launch_bounds__(256) void k2_mask(const float* __restrict__ gt,
                                               float* __restrict__ ws) {
  int tid = threadIdx.x;
  int n   = blockIdx.x >> 6;
  int pix = ((blockIdx.x & 63) << 8) | tid;
  float hf = (float)(pix >> 7), wf = (float)(pix & 127);

  __shared__ float bx[NBOX][5];
  __shared__ float l_bg[4];
  if (tid < NBOX) {
    const float* g = gt + (n * NBOX + tid) * 4;
    // gt/IMG*W with IMG=1024, W=H=128 -> exact *0.125f (powers of two)
    float wmin = floorf(g[0] * 0.125f);
    float hmin = floorf(g[1] * 0.125f);
    float wmax = ceilf(g[2] * 0.125f);
    float hmax = ceilf(g[3] * 0.125f);
    bx[tid][0] = wmin; bx[tid][1] = hmin; bx[tid][2] = wmax; bx[tid][3] = hmax;
    bx[tid][4] = 1.0f / ((hmax + 1.0f - hmin) * (wmax + 1.0f - wmin));
  }
  __syncthreads();

  float best = 0.f;
#pragma unroll
  for (int b = 0; b < NBOX; b++) {
    bool in = (hf >= bx[b][1]) && (hf <= bx[b][3]) && (wf >= bx[b][0]) && (wf <= bx[b][2]);
    best = in ? fmaxf(best, bx[b][4]) : best;
  }
  ws[OFF_MFG + n * HWHW + pix] = best;

  float bg = (best > 0.f) ? 0.f : 1.f;
  bg = dpp_wave_sum(bg);
  if ((tid & 63) == 63) l_bg[tid >> 6] = bg;
  __syncthreads();
  if (tid == 0) atomicAdd(&ws[OFF_BG + n], l_bg[0] + l_bg[1] + l_bg[2] + l_bg[3]);
}

// ---- K3: reductions of pass-1 partials + softmax stats + mask loss ----
// grid 8 (one block per n), block 256
__global__ __launch_bounds__(256) void k3_stats(float* __restrict__ ws) {
  int tid = threadIdx.x;
  int n   = blockIdx.x;
  __shared__ float sm[4];

  // (a) reduce per-block channel partials
  float chS = 0.f, chT = 0.f, Dv = 0.f;
  for (int k = 0; k < 64; k++) {
    int idx = (n * 64 + k) * CC + tid;
    chS += ws[OFF_PCHS + idx];
    chT += ws[OFF_PCHT + idx];
    Dv  += ws[OFF_PD + idx];
  }
  ws[OFF_CHS + n * CC + tid]  = chS;
  ws[OFF_CHT + n * CC + tid]  = chT;
  ws[OFF_DSUM + n * CC + tid] = Dv;

  // (b) channel attention softmax (logit = sum/HW/TEMP = sum/8192)
  const float chscale = 1.0f / 8192.0f;
  float lS = chS * chscale, lT = chT * chscale;
  float mS = block_max256(lS, sm);
  float mT = block_max256(lT, sm);
  float eS = expf(lS - mS), eT = expf(lT - mT);
  float ZS = block_sum256(eS, sm);
  float ZT = block_sum256(eT, sm);
  float cattS = (float)CC * eS / ZS;
  float cattT = (float)CC * eT / ZT;
  ws[OFF_CATT + n * CC + tid] = cattT;
  float mml = block_sum256(fabsf(cattS - cattT), sm);
  if (tid == 0) atomicAdd(&ws[OFF_SCAL + 2], mml);

  // (c) spatial stats for fea_S, fea_T (logit = sum/C/TEMP = sum/128) and cm_S, cm_T (logit = cm)
  float mxs[4], Zs[4];
  const int   offs[4]   = {OFF_FEA_S, OFF_FEA_T, OFF_CM_S, OFF_CM_T};
  const float scales[4] = {1.0f / 128.0f, 1.0f / 128.0f, 1.0f, 1.0f};
#pragma unroll
  for (int a = 0; a < 4; a++) {
    float mx = -1e30f;
    for (int i = tid; i < HWHW; i += 256)
      mx = fmaxf(mx, ws[offs[a] + n * HWHW + i] * scales[a]);
    mx = block_max256(mx, sm);
    float Z = 0.f;
    for (int i = tid; i < HWHW; i += 256)
      Z += expf(ws[offs[a] + n * HWHW + i] * scales[a] - mx);
    Z = block_sum256(Z, sm);
    mxs[a] = mx; Zs[a] = Z;
    if (tid == 0) { ws[OFF_STATS + n * 8 + 2 * a] = mx; ws[OFF_STATS + n * 8 + 2 * a + 1] = Z; }
  }

  // (d) spatial mask loss: HW * sum |softmax_s - softmax_t|
  float acc = 0.f;
  for (int i = tid; i < HWHW; i += 256) {
    float ls = ws[OFF_FEA_S + n * HWHW + i] * (1.0f / 128.0f);
    float lt = ws[OFF_FEA_T + n * HWHW + i] * (1.0f / 128.0f);
    float pS = expf(ls - mxs[0]) / Zs[0];
    float pT = expf(lt - mxs[1]) / Zs[1];
    acc += fabsf(pS - pT);
  }
  acc = block_sum256(acc, sm);
  if (tid == 0) atomicAdd(&ws[OFF_SCAL + 2], acc * (float)HWHW);
}

// ---- K4: pass 2 over S,T: fg/bg loss + ctx partial sums ----
__global__ __launch_bounds__(256) void k4_pass2(
    const float* __restrict__ S, const float* __restrict__ T,
    float* __restrict__ ws) {
  int tid  = threadIdx.x;
  int n    = blockIdx.x >> 6;
  int pix  = ((blockIdx.x & 63) << 8) | tid;
  int lane = tid & 63, wave = tid >> 6;

  __shared__ float l_catt[CC];
  __shared__ float l_cs[4][CC], l_ct[4][CC];
  __shared__ float l_c[4];
  l_catt[tid] = ws[OFF_CATT + n * CC + tid];

  float mxFT = ws[OFF_STATS + n * 8 + 2], ZFT = ws[OFF_STATS + n * 8 + 3];
  float mxCS = ws[OFF_STATS + n * 8 + 4], ZCS = ws[OFF_STATS + n * 8 + 5];
  float mxCT = ws[OFF_STATS + n * 8 + 6], ZCT = ws[OFF_STATS + n * 8 + 7];

  int gp = n * HWHW + pix;
  float Satt = (float)HWHW * expf(ws[OFF_FEA_T + gp] * (1.0f / 128.0f) - mxFT) / ZFT;
  float mfg  = ws[OFF_MFG + gp];
  float bgc  = ws[OFF_BG + n];
  float mbg  = (mfg > 0.f) ? 0.f : ((bgc > 0.f) ? 1.0f / bgc : 1.0f);
  float wcomb = Satt * (C_ALPHA * mfg + C_BETA * mbg);
  float sms = expf(ws[OFF_CM_S + gp] - mxCS) / ZCS;
  float smt = expf(ws[OFF_CM_T + gp] - mxCT) / ZCT;

  const float* ps = S + (size_t)n * CC * HWHW + pix;
  const float* pt = T + (size_t)n * CC * HWHW + pix;
  __syncthreads();

  float accw = 0.f;
#pragma unroll 4
  for (int c = 0; c < CC; c++) {
    float s = ps[c * HWHW], t = pt[c * HWHW];
    float d = s - t;
    accw = fmaf(d * d, l_catt[c], accw);
    float xs = s * sms, xt = t * smt;
    xs = dpp_wave_sum(xs);
    xt = dpp_wave_sum(xt);
    if (lane == 63) { l_cs[wave][c] = xs; l_ct[wave][c] = xt; }
  }
  __syncthreads();

  int bo = blockIdx.x * CC + tid;
  ws[OFF_PCTXS + bo] = l_cs[0][tid] + l_cs[1][tid] + l_cs[2][tid] + l_cs[3][tid];
  ws[OFF_PCTXT + bo] = l_ct[0][tid] + l_ct[1][tid] + l_ct[2][tid] + l_ct[3][tid];

  float contrib = dpp_wave_sum(accw * wcomb);
  if (lane == 63) l_c[wave] = contrib;
  __syncthreads();
  if (tid == 0) atomicAdd(&ws[OFF_SCAL + 1], l_c[0] + l_c[1] + l_c[2] + l_c[3]);
}

// ---- K4b: reduce ctx partials ----
__global__ __launch_bounds__(256) void k4b_ctxreduce(float* __restrict__ ws) {
  int tid = threadIdx.x;
  int n   = blockIdx.x;
  float a = 0.f, b = 0.f;
  for (int k = 0; k < 64; k++) {
    int idx = (n * 64 + k) * CC + tid;
    a += ws[OFF_PCTXS + idx];
    b += ws[OFF_PCTXT + idx];
  }
  ws[OFF_CTXS + n * CC + tid] = a;
  ws[OFF_CTXT + n * CC + tid] = b;
}

// ---- K5: tiny MLPs + final assembly ----
__global__ __launch_bounds__(256) void k5_final(
    const float* __restrict__ w1_s, const float* __restrict__ b1_s,
    const float* __restrict__ g_s,  const float* __restrict__ be_s,
    const float* __restrict__ w2_s, const float* __restrict__ b2_s,
    const float* __restrict__ w1_t, const float* __restrict__ b1_t,
    const float* __restrict__ g_t,  const float* __restrict__ be_t,
    const float* __restrict__ w2_t, const float* __restrict__ b2_t,
    float* __restrict__ ws, float* __restrict__ out) {
  int tid = threadIdx.x;
  __shared__ float ys[NN][CC / 2], yt[NN][CC / 2];
  __shared__ float sm[4];

  // y = ctx @ w1^T + b1
  for (int p = tid; p < NN * (CC / 2); p += 256) {
    int n = p >> 7, j = p & 127;
    float ds = b1_s[j], dt = b1_t[j];
    for (int c = 0; c < CC; c++) {
      ds = fmaf(ws[OFF_CTXS + n * CC + c], w1_s[j * CC + c], ds);
      dt = fmaf(ws[OFF_CTXT + n * CC + c], w1_t[j * CC + c], dt);
    }
    ys[n][j] = ds;
    yt[n][j] = dt;
  }
  __syncthreads();

  // LayerNorm + ReLU (tiny: 16 rows of 128)
  if (tid < 16) {
    int n = tid >> 1;
    bool isT = tid & 1;
    float* y = isT ? yt[n] : ys[n];
    const float* g  = isT ? g_t : g_s;
    const float* be = isT ? be_t : be_s;
    float m = 0.f;
    for (int j = 0; j < 128; j++) m += y[j];
    m *= (1.0f / 128.0f);
    float v = 0.f;
    for (int j = 0; j < 128; j++) { float d = y[j] - m; v += d * d; }
    v *= (1.0f / 128.0f);
    float inv = 1.0f / sqrtf(v + C_LN_EPS);
    for (int j = 0; j < 128; j++) {
      float q = (y[j] - m) * inv * g[j] + be[j];
      y[j] = q > 0.f ? q : 0.f;
    }
  }
  __syncthreads();

  // e[n,c] = add_s - add_t ; rela cross terms: 2*e*D + HW*e^2
  float rp = 0.f;
  for (int p = tid; p < NN * CC; p += 256) {
    int n = p >> 8, c = p & 255;
    float es = b2_s[c], et = b2_t[c];
    for (int j = 0; j < 128; j++) {
      es = fmaf(ys[n][j], w2_s[c * 128 + j], es);
      et = fmaf(yt[n][j], w2_t[c * 128 + j], et);
    }
    float e = es - et;
    rp += 2.0f * e * ws[OFF_DSUM + n * CC + c] + (float)HWHW * e * e;
  }
  rp = dpp_wave_sum(rp);
  if ((tid & 63) == 63) sm[tid >> 6] = rp;
  __syncthreads();
  if (tid == 0) {
    float rela = ws[OFF_SCAL + 0] + sm[0] + sm[1] + sm[2] + sm[3];
    float res = (ws[OFF_SCAL + 1] + C_GAMMA * ws[OFF_SCAL + 2] + C_LAMB * rela) * (1.0f / (float)NN);
    out[0] = res;
  }
}

extern "C" void kernel_launch(void* const* d_in, const int* in_sizes, int n_in,
                              void* d_out, int out_size, void* d_ws, size_t ws_size,
                              hipStream_t stream) {
  const float* S    = (const float*)d_in[0];
  const float* T    = (const float*)d_in[1];
  const float* gt   = (const float*)d_in[2];
  const float* w_ms = (const float*)d_in[3];
  const float* w_mt = (const float*)d_in[5];
  const float* w1_s = (const float*)d_in[7];
  const float* b1_s = (const float*)d_in[8];
  const float* g_s  = (const float*)d_in[9];
  const float* be_s = (const float*)d_in[10];
  const float* w2_s = (const float*)d_in[11];
  const float* b2_s = (const float*)d_in[12];
  const float* w1_t = (const float*)d_in[13];
  const float* b1_t = (const float*)d_in[14];
  const float* g_t  = (const float*)d_in[15];
  const float* be_t = (const float*)d_in[16];
  const float* w2_t = (const float*)d_in[17];
  const float* b2_t = (const float*)d_in[18];
  float* ws = (float*)d_ws;
  float* out = (float*)d_out;

  // zero only the atomically-accumulated region (bg counts + scalars)
  hipMemsetAsync(ws + OFF_BG, 0, 16 * sizeof(float), stream);

  k1_pass1<<<dim3(512), dim3(256), 0, stream>>>(S, T, w_ms, w_mt, ws);
  k2_mask<<<dim3(512), dim3(256), 0, stream>>>(gt, ws);
  k3_stats<<<dim3(8), dim3(256), 0, stream>>>(ws);
  k4_pass2<<<dim3(512), dim3(256), 0, stream>>>(S, T, ws);
  k4b_ctxreduce<<<dim3(8), dim3(256), 0, stream>>>(ws);
  k5_final<<<dim3(1), dim3(256), 0, stream>>>(w1_s, b1_s, g_s, be_s, w2_s, b2_s,
                                              w1_t, b1_t, g_t, be_t, w2_t, b2_t,
                                              ws, out);
}

// Round 2
// 570.209 us; speedup vs baseline: 1.4001x; 1.4001x over previous
//
#include <hip/hip_runtime.h>
#include <math.h>

#define NN    8
#define CC    256
#define HWHW  16384
#define NBOX  20

constexpr float C_ALPHA = 1e-3f, C_BETA = 5e-4f, C_GAMMA = 1e-3f, C_LAMB = 5e-6f;
constexpr float C_LN_EPS = 1e-5f;

// ws layout (float offsets)
#define OFF_FEA_S   0          // [N*HW] final per-pixel channel-abs-sum (S)
#define OFF_FEA_T   131072
#define OFF_CM_S    262144     // per-pixel context logit (S)
#define OFF_CM_T    393216
#define OFF_MFG     524288     // [N*HW]
#define OFF_PCHS    655360     // [N*C*64] per-(pixelblock) channel partials
#define OFF_PCHT    786432
#define OFF_PD      917504
#define OFF_PCTXS   1048576
#define OFF_PCTXT   1179648
#define OFF_CATT    1310720    // [N*C] C_att for T
#define OFF_CTXS    1312768
#define OFF_CTXT    1314816
#define OFF_DSUM    1316864
#define OFF_STATS   1318912    // [N*8] {mxFS,ZFS,mxFT,ZFT,mxCS,ZCS,mxCT,ZCT}
#define OFF_MXP     1318976    // [4*8*16] stage-1 maxes
#define OFF_ZP      1319488    // [4*8*16] stage-1 rescaled exp-sums
#define OFF_BG      1320000    // [8]
#define OFF_SCAL    1320008    // [8] 0: sum(S-T)^2, 1: fg/bg, 2: mask loss

// ---- wave-64 reductions via DPP ----
__device__ __forceinline__ float dpp_wave_sum(float x) {
#define DPPADD(ctrl, rm) \
  x += __int_as_float(__builtin_amdgcn_update_dpp(0, __float_as_int(x), ctrl, rm, 0xf, true));
  DPPADD(0x111, 0xf)
  DPPADD(0x112, 0xf)
  DPPADD(0x114, 0xf)
  DPPADD(0x118, 0xf)
  DPPADD(0x142, 0xa)
  DPPADD(0x143, 0xc)
#undef DPPADD
  return x;  // total in lane 63
}

__device__ __forceinline__ float dpp_wave_max(float x) {
#define DPPMAX(ctrl, rm) { \
  int r_ = __builtin_amdgcn_update_dpp(__float_as_int(x), __float_as_int(x), ctrl, rm, 0xf, false); \
  x = fmaxf(x, __int_as_float(r_)); }
  DPPMAX(0x111, 0xf)
  DPPMAX(0x112, 0xf)
  DPPMAX(0x114, 0xf)
  DPPMAX(0x118, 0xf)
  DPPMAX(0x142, 0xa)
  DPPMAX(0x143, 0xc)
#undef DPPMAX
  return x;
}

__device__ __forceinline__ float block_sum256(float v, float* sm) {
  int tid = threadIdx.x;
  v = dpp_wave_sum(v);
  if ((tid & 63) == 63) sm[tid >> 6] = v;
  __syncthreads();
  float r = sm[0] + sm[1] + sm[2] + sm[3];
  __syncthreads();
  return r;
}

__device__ __forceinline__ float block_max256(float v, float* sm) {
  int tid = threadIdx.x;
  v = dpp_wave_max(v);
  if ((tid & 63) == 63) sm[tid >> 6] = v;
  __syncthreads();
  float r = fmaxf(fmaxf(sm[0], sm[1]), fmaxf(sm[2], sm[3]));
  __syncthreads();
  return r;
}

// ---- K1: pass 1. grid (64 pixblocks, 8 n) x 512 thr.
// 8 waves = 8 channel slices of 32; lane owns 4 pixels (float4).
__global__ __launch_bounds__(512, 4) void k1_pass1(
    const float* __restrict__ S, const float* __restrict__ T,
    const float* __restrict__ w_ms, const float* __restrict__ w_mt,
    float* __restrict__ ws) {
  int tid = threadIdx.x;
  int lane = tid & 63, sl = tid >> 6;
  int pb = blockIdx.x, n = blockIdx.y;
  int pix0 = pb * 256 + lane * 4;

  __shared__ float l_ws[CC], l_wt[CC];
  __shared__ float f_feaS[256], f_feaT[256], f_cmS[256], f_cmT[256];
  __shared__ float l_chS[CC], l_chT[CC], l_D[CC];
  __shared__ float l_sq[8];

  if (tid < 256) {
    l_ws[tid] = w_ms[tid]; l_wt[tid] = w_mt[tid];
    f_feaS[tid] = 0.f; f_feaT[tid] = 0.f; f_cmS[tid] = 0.f; f_cmT[tid] = 0.f;
  }
  __syncthreads();

  const float* baseS = S + (size_t)(n * CC + sl * 32) * HWHW + pix0;
  const float* baseT = T + (size_t)(n * CC + sl * 32) * HWHW + pix0;

  float fSx = 0, fSy = 0, fSz = 0, fSw = 0;
  float fTx = 0, fTy = 0, fTz = 0, fTw = 0;
  float cSx = 0, cSy = 0, cSz = 0, cSw = 0;
  float cTx = 0, cTy = 0, cTz = 0, cTw = 0;
  float sq = 0.f;

#pragma unroll 4
  for (int c = 0; c < 32; c++) {
    float4 s4 = *(const float4*)(baseS + (size_t)c * HWHW);
    float4 t4 = *(const float4*)(baseT + (size_t)c * HWHW);
    float asx = fabsf(s4.x), asy = fabsf(s4.y), asz = fabsf(s4.z), asw = fabsf(s4.w);
    float atx = fabsf(t4.x), aty = fabsf(t4.y), atz = fabsf(t4.z), atw = fabsf(t4.w);
    fSx += asx; fSy += asy; fSz += asz; fSw += asw;
    fTx += atx; fTy += aty; fTz += atz; fTw += atw;
    float wS = l_ws[sl * 32 + c], wT = l_wt[sl * 32 + c];
    cSx = fmaf(s4.x, wS, cSx); cSy = fmaf(s4.y, wS, cSy);
    cSz = fmaf(s4.z, wS, cSz); cSw = fmaf(s4.w, wS, cSw);
    cTx = fmaf(t4.x, wT, cTx); cTy = fmaf(t4.y, wT, cTy);
    cTz = fmaf(t4.z, wT, cTz); cTw = fmaf(t4.w, wT, cTw);
    float dx = s4.x - t4.x, dy = s4.y - t4.y, dz = s4.z - t4.z, dw = s4.w - t4.w;
    sq = fmaf(dx, dx, sq); sq = fmaf(dy, dy, sq);
    sq = fmaf(dz, dz, sq); sq = fmaf(dw, dw, sq);
    float chS_p = (asx + asy) + (asz + asw);
    float chT_p = (atx + aty) + (atz + atw);
    float d_p   = (dx + dy) + (dz + dw);
    chS_p = dpp_wave_sum(chS_p);
    chT_p = dpp_wave_sum(chT_p);
    d_p   = dpp_wave_sum(d_p);
    if (lane == 63) {
      l_chS[sl * 32 + c] = chS_p;
      l_chT[sl * 32 + c] = chT_p;
      l_D[sl * 32 + c]   = d_p;
    }
  }

  // combine per-pixel sums across the 8 slices via LDS atomics
  atomicAdd(&f_feaS[lane * 4 + 0], fSx); atomicAdd(&f_feaS[lane * 4 + 1], fSy);
  atomicAdd(&f_feaS[lane * 4 + 2], fSz); atomicAdd(&f_feaS[lane * 4 + 3], fSw);
  atomicAdd(&f_feaT[lane * 4 + 0], fTx); atomicAdd(&f_feaT[lane * 4 + 1], fTy);
  atomicAdd(&f_feaT[lane * 4 + 2], fTz); atomicAdd(&f_feaT[lane * 4 + 3], fTw);
  atomicAdd(&f_cmS[lane * 4 + 0], cSx); atomicAdd(&f_cmS[lane * 4 + 1], cSy);
  atomicAdd(&f_cmS[lane * 4 + 2], cSz); atomicAdd(&f_cmS[lane * 4 + 3], cSw);
  atomicAdd(&f_cmT[lane * 4 + 0], cTx); atomicAdd(&f_cmT[lane * 4 + 1], cTy);
  atomicAdd(&f_cmT[lane * 4 + 2], cTz); atomicAdd(&f_cmT[lane * 4 + 3], cTw);

  sq = dpp_wave_sum(sq);
  if (lane == 63) l_sq[sl] = sq;
  __syncthreads();

  if (tid < 256) {
    int gp = n * HWHW + pb * 256 + tid;
    ws[OFF_FEA_S + gp] = f_feaS[tid];
    ws[OFF_FEA_T + gp] = f_feaT[tid];
    ws[OFF_CM_S + gp]  = f_cmS[tid];
    ws[OFF_CM_T + gp]  = f_cmT[tid];
    int bo = (n * CC + tid) * 64 + pb;
    ws[OFF_PCHS + bo] = l_chS[tid];
    ws[OFF_PCHT + bo] = l_chT[tid];
    ws[OFF_PD + bo]   = l_D[tid];
  }
  if (tid == 0) {
    float t = 0.f;
#pragma unroll
    for (int i = 0; i < 8; i++) t += l_sq[i];
    atomicAdd(&ws[OFF_SCAL + 0], t);
  }
}

// ---- K2: foreground mask + bg pixel count ----
__global__ __launch_bounds__(256) void k2_mask(const float* __restrict__ gt,
                                               float* __restrict__ ws) {
  int tid = threadIdx.x;
  int n   = blockIdx.x >> 6;
  int pix = ((blockIdx.x & 63) << 8) | tid;
  float hf = (float)(pix >> 7), wf = (float)(pix & 127);

  __shared__ float bx[NBOX][5];
  __shared__ float l_bg[4];
  if (tid < NBOX) {
    const float* g = gt + (n * NBOX + tid) * 4;
    float wmin = floorf(g[0] * 0.125f);
    float hmin = floorf(g[1] * 0.125f);
    float wmax = ceilf(g[2] * 0.125f);
    float hmax = ceilf(g[3] * 0.125f);
    bx[tid][0] = wmin; bx[tid][1] = hmin; bx[tid][2] = wmax; bx[tid][3] = hmax;
    bx[tid][4] = 1.0f / ((hmax + 1.0f - hmin) * (wmax + 1.0f - wmin));
  }
  __syncthreads();

  float best = 0.f;
#pragma unroll
  for (int b = 0; b < NBOX; b++) {
    bool in = (hf >= bx[b][1]) && (hf <= bx[b][3]) && (wf >= bx[b][0]) && (wf <= bx[b][2]);
    best = in ? fmaxf(best, bx[b][4]) : best;
  }
  ws[OFF_MFG + n * HWHW + pix] = best;

  float bg = (best > 0.f) ? 0.f : 1.f;
  bg = dpp_wave_sum(bg);
  if ((tid & 63) == 63) l_bg[tid >> 6] = bg;
  __syncthreads();
  if (tid == 0) atomicAdd(&ws[OFF_BG + n], l_bg[0] + l_bg[1] + l_bg[2] + l_bg[3]);
}

// ---- KB: stage-1 softmax stats (local max + rescalable Z) over 1024-pixel tiles
// grid (16 pb, 8 n) x 256 thr, 4 px/thread
__global__ __launch_bounds__(256) void kB_stats1(float* __restrict__ ws) {
  int tid = threadIdx.x;
  int pb = blockIdx.x, n = blockIdx.y;
  __shared__ float sm[4];
  int pix0 = pb * 1024 + tid * 4;
  const int   offs[4]   = {OFF_FEA_S, OFF_FEA_T, OFF_CM_S, OFF_CM_T};
  const float scales[4] = {1.0f / 128.0f, 1.0f / 128.0f, 1.0f, 1.0f};
#pragma unroll
  for (int a = 0; a < 4; a++) {
    float4 v = *(const float4*)&ws[offs[a] + n * HWHW + pix0];
    float sc = scales[a];
    v.x *= sc; v.y *= sc; v.z *= sc; v.w *= sc;
    float mx = fmaxf(fmaxf(v.x, v.y), fmaxf(v.z, v.w));
    mx = block_max256(mx, sm);
    float z = expf(v.x - mx) + expf(v.y - mx) + expf(v.z - mx) + expf(v.w - mx);
    z = block_sum256(z, sm);
    if (tid == 0) {
      ws[OFF_MXP + a * 128 + n * 16 + pb] = mx;
      ws[OFF_ZP + a * 128 + n * 16 + pb]  = z;
    }
  }
}

// ---- KC: channel reductions + channel softmax + stats combine. grid 8 x 256
__global__ __launch_bounds__(256) void kC_stats2(float* __restrict__ ws) {
  int tid = threadIdx.x, n = blockIdx.x;
  __shared__ float sm[4];

  float chS = 0.f, chT = 0.f, Dv = 0.f;
  int base = (n * CC + tid) * 64;
#pragma unroll 4
  for (int k = 0; k < 64; k += 4) {
    float4 a = *(const float4*)&ws[OFF_PCHS + base + k];
    float4 b = *(const float4*)&ws[OFF_PCHT + base + k];
    float4 d = *(const float4*)&ws[OFF_PD + base + k];
    chS += (a.x + a.y) + (a.z + a.w);
    chT += (b.x + b.y) + (b.z + b.w);
    Dv  += (d.x + d.y) + (d.z + d.w);
  }
  ws[OFF_DSUM + n * CC + tid] = Dv;

  float lS = chS * (1.0f / 8192.0f), lT = chT * (1.0f / 8192.0f);
  float mS = block_max256(lS, sm);
  float mT = block_max256(lT, sm);
  float eS = expf(lS - mS), eT = expf(lT - mT);
  float ZS = block_sum256(eS, sm);
  float ZT = block_sum256(eT, sm);
  float cattS = (float)CC * eS / ZS;
  float cattT = (float)CC * eT / ZT;
  ws[OFF_CATT + n * CC + tid] = cattT;
  float mml = block_sum256(fabsf(cattS - cattT), sm);
  if (tid == 0) atomicAdd(&ws[OFF_SCAL + 2], mml);

  if (tid < 4) {
    int a = tid;
    float m = -1e30f;
    for (int i = 0; i < 16; i++)
      m = fmaxf(m, ws[OFF_MXP + a * 128 + n * 16 + i]);
    float Z = 0.f;
    for (int i = 0; i < 16; i++)
      Z += ws[OFF_ZP + a * 128 + n * 16 + i] *
           expf(ws[OFF_MXP + a * 128 + n * 16 + i] - m);
    ws[OFF_STATS + n * 8 + 2 * a]     = m;
    ws[OFF_STATS + n * 8 + 2 * a + 1] = Z;
  }
}

// ---- K4: pass 2. same decomposition as K1.
__global__ __launch_bounds__(512, 4) void k4_pass2(
    const float* __restrict__ S, const float* __restrict__ T,
    float* __restrict__ ws) {
  int tid = threadIdx.x;
  int lane = tid & 63, sl = tid >> 6;
  int pb = blockIdx.x, n = blockIdx.y;
  int pix0 = pb * 256 + lane * 4;

  __shared__ float l_catt[CC];
  __shared__ float wcombL[256], smsL[256], smtL[256];
  __shared__ float l_cs[CC], l_ct[CC], l_c[8];

  if (tid < 256) l_catt[tid] = ws[OFF_CATT + n * CC + tid];
  if (tid < 64) {
    float mxFS = ws[OFF_STATS + n * 8 + 0], ZFS = ws[OFF_STATS + n * 8 + 1];
    float mxFT = ws[OFF_STATS + n * 8 + 2], ZFT = ws[OFF_STATS + n * 8 + 3];
    float mxCS = ws[OFF_STATS + n * 8 + 4], ZCS = ws[OFF_STATS + n * 8 + 5];
    float mxCT = ws[OFF_STATS + n * 8 + 6], ZCT = ws[OFF_STATS + n * 8 + 7];
    float bgc  = ws[OFF_BG + n];
    int gp = n * HWHW + pb * 256 + tid * 4;
    float4 fS = *(const float4*)&ws[OFF_FEA_S + gp];
    float4 fT = *(const float4*)&ws[OFF_FEA_T + gp];
    float4 cS = *(const float4*)&ws[OFF_CM_S + gp];
    float4 cT = *(const float4*)&ws[OFF_CM_T + gp];
    float4 mf = *(const float4*)&ws[OFF_MFG + gp];
    float macc = 0.f;
    float fSa[4] = {fS.x, fS.y, fS.z, fS.w};
    float fTa[4] = {fT.x, fT.y, fT.z, fT.w};
    float cSa[4] = {cS.x, cS.y, cS.z, cS.w};
    float cTa[4] = {cT.x, cT.y, cT.z, cT.w};
    float mfa[4] = {mf.x, mf.y, mf.z, mf.w};
#pragma unroll
    for (int j = 0; j < 4; j++) {
      float pT = expf(fTa[j] * (1.0f / 128.0f) - mxFT) / ZFT;
      float pS = expf(fSa[j] * (1.0f / 128.0f) - mxFS) / ZFS;
      float Satt = (float)HWHW * pT;
      float mbg = (mfa[j] > 0.f) ? 0.f : ((bgc > 0.f) ? 1.0f / bgc : 1.0f);
      wcombL[tid * 4 + j] = Satt * (C_ALPHA * mfa[j] + C_BETA * mbg);
      smsL[tid * 4 + j] = expf(cSa[j] - mxCS) / ZCS;
      smtL[tid * 4 + j] = expf(cTa[j] - mxCT) / ZCT;
      macc += fabsf(pS - pT);
    }
    macc = dpp_wave_sum(macc);
    if (tid == 63) atomicAdd(&ws[OFF_SCAL + 2], macc * (float)HWHW);
  }
  __syncthreads();

  float4 sms = *(const float4*)&smsL[lane * 4];
  float4 smt = *(const float4*)&smtL[lane * 4];
  float4 wcb = *(const float4*)&wcombL[lane * 4];

  const float* baseS = S + (size_t)(n * CC + sl * 32) * HWHW + pix0;
  const float* baseT = T + (size_t)(n * CC + sl * 32) * HWHW + pix0;

  float awx = 0, awy = 0, awz = 0, aww = 0;
#pragma unroll 4
  for (int c = 0; c < 32; c++) {
    float4 s4 = *(const float4*)(baseS + (size_t)c * HWHW);
    float4 t4 = *(const float4*)(baseT + (size_t)c * HWHW);
    float ca = l_catt[sl * 32 + c];
    float dx = s4.x - t4.x, dy = s4.y - t4.y, dz = s4.z - t4.z, dw = s4.w - t4.w;
    awx = fmaf(dx * dx, ca, awx); awy = fmaf(dy * dy, ca, awy);
    awz = fmaf(dz * dz, ca, awz); aww = fmaf(dw * dw, ca, aww);
    float xs = fmaf(s4.x, sms.x, fmaf(s4.y, sms.y, fmaf(s4.z, sms.z, s4.w * sms.w)));
    float xt = fmaf(t4.x, smt.x, fmaf(t4.y, smt.y, fmaf(t4.z, smt.z, t4.w * smt.w)));
    xs = dpp_wave_sum(xs);
    xt = dpp_wave_sum(xt);
    if (lane == 63) { l_cs[sl * 32 + c] = xs; l_ct[sl * 32 + c] = xt; }
  }

  float contrib = fmaf(awx, wcb.x, fmaf(awy, wcb.y, fmaf(awz, wcb.z, aww * wcb.w)));
  contrib = dpp_wave_sum(contrib);
  if (lane == 63) l_c[sl] = contrib;
  __syncthreads();

  if (tid < 256) {
    int bo = (n * CC + tid) * 64 + pb;
    ws[OFF_PCTXS + bo] = l_cs[tid];
    ws[OFF_PCTXT + bo] = l_ct[tid];
  }
  if (tid == 0) {
    float t = 0.f;
#pragma unroll
    for (int i = 0; i < 8; i++) t += l_c[i];
    atomicAdd(&ws[OFF_SCAL + 1], t);
  }
}

// ---- K4b: reduce ctx partials. grid 8 x 256
__global__ __launch_bounds__(256) void k4b_ctxreduce(float* __restrict__ ws) {
  int tid = threadIdx.x, n = blockIdx.x;
  float a = 0.f, b = 0.f;
  int base = (n * CC + tid) * 64;
#pragma unroll 4
  for (int k = 0; k < 64; k += 4) {
    float4 x = *(const float4*)&ws[OFF_PCTXS + base + k];
    float4 y = *(const float4*)&ws[OFF_PCTXT + base + k];
    a += (x.x + x.y) + (x.z + x.w);
    b += (y.x + y.y) + (y.z + y.w);
  }
  ws[OFF_CTXS + n * CC + tid] = a;
  ws[OFF_CTXT + n * CC + tid] = b;
}

// ---- K5: tiny MLPs + final assembly ----
__global__ __launch_bounds__(256) void k5_final(
    const float* __restrict__ w1_s, const float* __restrict__ b1_s,
    const float* __restrict__ g_s,  const float* __restrict__ be_s,
    const float* __restrict__ w2_s, const float* __restrict__ b2_s,
    const float* __restrict__ w1_t, const float* __restrict__ b1_t,
    const float* __restrict__ g_t,  const float* __restrict__ be_t,
    const float* __restrict__ w2_t, const float* __restrict__ b2_t,
    float* __restrict__ ws, float* __restrict__ out) {
  int tid = threadIdx.x;
  __shared__ float ys[NN][CC / 2], yt[NN][CC / 2];
  __shared__ float sm[4];

  for (int p = tid; p < NN * (CC / 2); p += 256) {
    int n = p >> 7, j = p & 127;
    float ds = b1_s[j], dt = b1_t[j];
    for (int c = 0; c < CC; c++) {
      ds = fmaf(ws[OFF_CTXS + n * CC + c], w1_s[j * CC + c], ds);
      dt = fmaf(ws[OFF_CTXT + n * CC + c], w1_t[j * CC + c], dt);
    }
    ys[n][j] = ds;
    yt[n][j] = dt;
  }
  __syncthreads();

  if (tid < 16) {
    int n = tid >> 1;
    bool isT = tid & 1;
    float* y = isT ? yt[n] : ys[n];
    const float* g  = isT ? g_t : g_s;
    const float* be = isT ? be_t : be_s;
    float m = 0.f;
    for (int j = 0; j < 128; j++) m += y[j];
    m *= (1.0f / 128.0f);
    float v = 0.f;
    for (int j = 0; j < 128; j++) { float d = y[j] - m; v += d * d; }
    v *= (1.0f / 128.0f);
    float inv = 1.0f / sqrtf(v + C_LN_EPS);
    for (int j = 0; j < 128; j++) {
      float q = (y[j] - m) * inv * g[j] + be[j];
      y[j] = q > 0.f ? q : 0.f;
    }
  }
  __syncthreads();

  float rp = 0.f;
  for (int p = tid; p < NN * CC; p += 256) {
    int n = p >> 8, c = p & 255;
    float es = b2_s[c], et = b2_t[c];
    for (int j = 0; j < 128; j++) {
      es = fmaf(ys[n][j], w2_s[c * 128 + j], es);
      et = fmaf(yt[n][j], w2_t[c * 128 + j], et);
    }
    float e = es - et;
    rp += 2.0f * e * ws[OFF_DSUM + n * CC + c] + (float)HWHW * e * e;
  }
  rp = dpp_wave_sum(rp);
  if ((tid & 63) == 63) sm[tid >> 6] = rp;
  __syncthreads();
  if (tid == 0) {
    float rela = ws[OFF_SCAL + 0] + sm[0] + sm[1] + sm[2] + sm[3];
    float res = (ws[OFF_SCAL + 1] + C_GAMMA * ws[OFF_SCAL + 2] + C_LAMB * rela) * (1.0f / (float)NN);
    out[0] = res;
  }
}

extern "C" void kernel_launch(void* const* d_in, const int* in_sizes, int n_in,
                              void* d_out, int out_size, void* d_ws, size_t ws_size,
                              hipStream_t stream) {
  const float* S    = (const float*)d_in[0];
  const float* T    = (const float*)d_in[1];
  const float* gt   = (const float*)d_in[2];
  const float* w_ms = (const float*)d_in[3];
  const float* w_mt = (const float*)d_in[5];
  const float* w1_s = (const float*)d_in[7];
  const float* b1_s = (const float*)d_in[8];
  const float* g_s  = (const float*)d_in[9];
  const float* be_s = (const float*)d_in[10];
  const float* w2_s = (const float*)d_in[11];
  const float* b2_s = (const float*)d_in[12];
  const float* w1_t = (const float*)d_in[13];
  const float* b1_t = (const float*)d_in[14];
  const float* g_t  = (const float*)d_in[15];
  const float* be_t = (const float*)d_in[16];
  const float* w2_t = (const float*)d_in[17];
  const float* b2_t = (const float*)d_in[18];
  float* ws = (float*)d_ws;
  float* out = (float*)d_out;

  hipMemsetAsync(ws + OFF_BG, 0, 16 * sizeof(float), stream);

  k1_pass1<<<dim3(64, 8), dim3(512), 0, stream>>>(S, T, w_ms, w_mt, ws);
  k2_mask<<<dim3(512), dim3(256), 0, stream>>>(gt, ws);
  kB_stats1<<<dim3(16, 8), dim3(256), 0, stream>>>(ws);
  kC_stats2<<<dim3(8), dim3(256), 0, stream>>>(ws);
  k4_pass2<<<dim3(64, 8), dim3(512), 0, stream>>>(S, T, ws);
  k4b_ctxreduce<<<dim3(8), dim3(256), 0, stream>>>(ws);
  k5_final<<<dim3(1), dim3(256), 0, stream>>>(w1_s, b1_s, g_s, be_s, w2_s, b2_s,
                                              w1_t, b1_t, g_t, be_t, w2_t, b2_t,
                                              ws, out);
}

// Round 3
// 447.706 us; speedup vs baseline: 1.7832x; 1.2736x over previous
//
#include <hip/hip_runtime.h>
#include <math.h>

#define NN    8
#define CC    256
#define HWHW  16384
#define NBOX  20

constexpr float C_ALPHA = 1e-3f, C_BETA = 5e-4f, C_GAMMA = 1e-3f, C_LAMB = 5e-6f;
constexpr float C_LN_EPS = 1e-5f;

// ws layout (float offsets)
#define OFF_FEA_S   0          // [N*HW] combined via global atomicAdd (memset 0)
#define OFF_FEA_T   131072
#define OFF_CM_S    262144
#define OFF_CM_T    393216
#define OFF_MFG     524288     // [N*HW]
#define OFF_PCHS    655360     // [N*C*64] per-pixblock channel partials
#define OFF_PCHT    786432
#define OFF_PD      917504
#define OFF_PCTXS   1048576
#define OFF_PCTXT   1179648
#define OFF_CATT    1310720    // [N*C]
#define OFF_CTXS    1312768
#define OFF_CTXT    1314816
#define OFF_DSUM    1316864
#define OFF_STATS   1318912    // [N*8] {mxFS,ZFS,mxFT,ZFT,mxCS,ZCS,mxCT,ZCT}
#define OFF_MXP     1318976    // [4*8*16]
#define OFF_ZP      1319488
#define OFF_BG      1320000    // [8]
#define OFF_SCAL    1320008    // [8] 0: sum(S-T)^2, 1: fg/bg, 2: mask loss
#define OFF_Y       1320016    // [16*128] post-LN/ReLU hidden
#define OFF_RELAP   1322064    // [8] per-n rela cross partials

// ---- wave-64 reductions via DPP ----
__device__ __forceinline__ float dpp_wave_sum(float x) {
#define DPPADD(ctrl, rm) \
  x += __int_as_float(__builtin_amdgcn_update_dpp(0, __float_as_int(x), ctrl, rm, 0xf, true));
  DPPADD(0x111, 0xf)
  DPPADD(0x112, 0xf)
  DPPADD(0x114, 0xf)
  DPPADD(0x118, 0xf)
  DPPADD(0x142, 0xa)
  DPPADD(0x143, 0xc)
#undef DPPADD
  return x;  // total in lane 63
}

__device__ __forceinline__ float dpp_wave_max(float x) {
#define DPPMAX(ctrl, rm) { \
  int r_ = __builtin_amdgcn_update_dpp(__float_as_int(x), __float_as_int(x), ctrl, rm, 0xf, false); \
  x = fmaxf(x, __int_as_float(r_)); }
  DPPMAX(0x111, 0xf)
  DPPMAX(0x112, 0xf)
  DPPMAX(0x114, 0xf)
  DPPMAX(0x118, 0xf)
  DPPMAX(0x142, 0xa)
  DPPMAX(0x143, 0xc)
#undef DPPMAX
  return x;
}

__device__ __forceinline__ float block_sum256(float v, float* sm) {
  int tid = threadIdx.x;
  v = dpp_wave_sum(v);
  if ((tid & 63) == 63) sm[tid >> 6] = v;
  __syncthreads();
  float r = sm[0] + sm[1] + sm[2] + sm[3];
  __syncthreads();
  return r;
}

__device__ __forceinline__ float block_max256(float v, float* sm) {
  int tid = threadIdx.x;
  v = dpp_wave_max(v);
  if ((tid & 63) == 63) sm[tid >> 6] = v;
  __syncthreads();
  float r = fmaxf(fmaxf(sm[0], sm[1]), fmaxf(sm[2], sm[3]));
  __syncthreads();
  return r;
}

// ---- K1: pass 1. grid (64 pb, 2 cs, 8 n) x 512 thr.
// wave = 16-channel slice within this half; lane owns 4 pixels (float4).
__global__ __launch_bounds__(512, 8) void k1_pass1(
    const float* __restrict__ S, const float* __restrict__ T,
    const float* __restrict__ w_ms, const float* __restrict__ w_mt,
    float* __restrict__ ws) {
  int tid = threadIdx.x;
  int lane = tid & 63, sl = tid >> 6;
  int pb = blockIdx.x, cs = blockIdx.y, n = blockIdx.z;
  int pix0 = pb * 256 + lane * 4;
  int ch0 = cs * 128 + sl * 16;

  __shared__ float l_wS[128], l_wT[128];
  __shared__ float f_feaS[256], f_feaT[256], f_cmS[256], f_cmT[256];
  __shared__ float l_chS[128], l_chT[128], l_D[128];
  __shared__ float l_sq[8];

  if (tid < 128) {
    l_wS[tid] = w_ms[cs * 128 + tid];
    l_wT[tid] = w_mt[cs * 128 + tid];
  }
  if (tid < 256) {
    f_feaS[tid] = 0.f; f_feaT[tid] = 0.f; f_cmS[tid] = 0.f; f_cmT[tid] = 0.f;
  }
  __syncthreads();

  const float* baseS = S + (size_t)(n * CC + ch0) * HWHW + pix0;
  const float* baseT = T + (size_t)(n * CC + ch0) * HWHW + pix0;

  float fSx = 0, fSy = 0, fSz = 0, fSw = 0;
  float fTx = 0, fTy = 0, fTz = 0, fTw = 0;
  float cSx = 0, cSy = 0, cSz = 0, cSw = 0;
  float cTx = 0, cTy = 0, cTz = 0, cTw = 0;
  float sq = 0.f;

#pragma unroll 2
  for (int c = 0; c < 16; c++) {
    float4 s4 = *(const float4*)(baseS + (size_t)c * HWHW);
    float4 t4 = *(const float4*)(baseT + (size_t)c * HWHW);
    float asx = fabsf(s4.x), asy = fabsf(s4.y), asz = fabsf(s4.z), asw = fabsf(s4.w);
    float atx = fabsf(t4.x), aty = fabsf(t4.y), atz = fabsf(t4.z), atw = fabsf(t4.w);
    fSx += asx; fSy += asy; fSz += asz; fSw += asw;
    fTx += atx; fTy += aty; fTz += atz; fTw += atw;
    float wS = l_wS[sl * 16 + c], wT = l_wT[sl * 16 + c];
    cSx = fmaf(s4.x, wS, cSx); cSy = fmaf(s4.y, wS, cSy);
    cSz = fmaf(s4.z, wS, cSz); cSw = fmaf(s4.w, wS, cSw);
    cTx = fmaf(t4.x, wT, cTx); cTy = fmaf(t4.y, wT, cTy);
    cTz = fmaf(t4.z, wT, cTz); cTw = fmaf(t4.w, wT, cTw);
    float dx = s4.x - t4.x, dy = s4.y - t4.y, dz = s4.z - t4.z, dw = s4.w - t4.w;
    sq = fmaf(dx, dx, sq); sq = fmaf(dy, dy, sq);
    sq = fmaf(dz, dz, sq); sq = fmaf(dw, dw, sq);
    float chS_p = (asx + asy) + (asz + asw);
    float chT_p = (atx + aty) + (atz + atw);
    float d_p   = (dx + dy) + (dz + dw);
    chS_p = dpp_wave_sum(chS_p);
    chT_p = dpp_wave_sum(chT_p);
    d_p   = dpp_wave_sum(d_p);
    if (lane == 63) {
      l_chS[sl * 16 + c] = chS_p;
      l_chT[sl * 16 + c] = chT_p;
      l_D[sl * 16 + c]   = d_p;
    }
  }

  atomicAdd(&f_feaS[lane * 4 + 0], fSx); atomicAdd(&f_feaS[lane * 4 + 1], fSy);
  atomicAdd(&f_feaS[lane * 4 + 2], fSz); atomicAdd(&f_feaS[lane * 4 + 3], fSw);
  atomicAdd(&f_feaT[lane * 4 + 0], fTx); atomicAdd(&f_feaT[lane * 4 + 1], fTy);
  atomicAdd(&f_feaT[lane * 4 + 2], fTz); atomicAdd(&f_feaT[lane * 4 + 3], fTw);
  atomicAdd(&f_cmS[lane * 4 + 0], cSx); atomicAdd(&f_cmS[lane * 4 + 1], cSy);
  atomicAdd(&f_cmS[lane * 4 + 2], cSz); atomicAdd(&f_cmS[lane * 4 + 3], cSw);
  atomicAdd(&f_cmT[lane * 4 + 0], cTx); atomicAdd(&f_cmT[lane * 4 + 1], cTy);
  atomicAdd(&f_cmT[lane * 4 + 2], cTz); atomicAdd(&f_cmT[lane * 4 + 3], cTw);

  sq = dpp_wave_sum(sq);
  if (lane == 63) l_sq[sl] = sq;
  __syncthreads();

  if (tid < 256) {
    int gp = n * HWHW + pb * 256 + tid;
    atomicAdd(&ws[OFF_FEA_S + gp], f_feaS[tid]);
    atomicAdd(&ws[OFF_FEA_T + gp], f_feaT[tid]);
    atomicAdd(&ws[OFF_CM_S + gp],  f_cmS[tid]);
    atomicAdd(&ws[OFF_CM_T + gp],  f_cmT[tid]);
  }
  if (tid < 128) {
    int bo = (n * CC + cs * 128 + tid) * 64 + pb;
    ws[OFF_PCHS + bo] = l_chS[tid];
    ws[OFF_PCHT + bo] = l_chT[tid];
    ws[OFF_PD + bo]   = l_D[tid];
  }
  if (tid == 0) {
    float t = 0.f;
#pragma unroll
    for (int i = 0; i < 8; i++) t += l_sq[i];
    atomicAdd(&ws[OFF_SCAL + 0], t);
  }
}

// ---- K2: foreground mask + bg pixel count ----
__global__ __launch_bounds__(256) void k2_mask(const float* __restrict__ gt,
                                               float* __restrict__ ws) {
  int tid = threadIdx.x;
  int n   = blockIdx.x >> 6;
  int pix = ((blockIdx.x & 63) << 8) | tid;
  float hf = (float)(pix >> 7), wf = (float)(pix & 127);

  __shared__ float bx[NBOX][5];
  __shared__ float l_bg[4];
  if (tid < NBOX) {
    const float* g = gt + (n * NBOX + tid) * 4;
    float wmin = floorf(g[0] * 0.125f);
    float hmin = floorf(g[1] * 0.125f);
    float wmax = ceilf(g[2] * 0.125f);
    float hmax = ceilf(g[3] * 0.125f);
    bx[tid][0] = wmin; bx[tid][1] = hmin; bx[tid][2] = wmax; bx[tid][3] = hmax;
    bx[tid][4] = 1.0f / ((hmax + 1.0f - hmin) * (wmax + 1.0f - wmin));
  }
  __syncthreads();

  float best = 0.f;
#pragma unroll
  for (int b = 0; b < NBOX; b++) {
    bool in = (hf >= bx[b][1]) && (hf <= bx[b][3]) && (wf >= bx[b][0]) && (wf <= bx[b][2]);
    best = in ? fmaxf(best, bx[b][4]) : best;
  }
  ws[OFF_MFG + n * HWHW + pix] = best;

  float bg = (best > 0.f) ? 0.f : 1.f;
  bg = dpp_wave_sum(bg);
  if ((tid & 63) == 63) l_bg[tid >> 6] = bg;
  __syncthreads();
  if (tid == 0) atomicAdd(&ws[OFF_BG + n], l_bg[0] + l_bg[1] + l_bg[2] + l_bg[3]);
}

// ---- KB: stage-1 softmax stats over 1024-pixel tiles. grid (16,8) x 256
__global__ __launch_bounds__(256) void kB_stats1(float* __restrict__ ws) {
  int tid = threadIdx.x;
  int pb = blockIdx.x, n = blockIdx.y;
  __shared__ float sm[4];
  int pix0 = pb * 1024 + tid * 4;
  const int   offs[4]   = {OFF_FEA_S, OFF_FEA_T, OFF_CM_S, OFF_CM_T};
  const float scales[4] = {1.0f / 128.0f, 1.0f / 128.0f, 1.0f, 1.0f};
#pragma unroll
  for (int a = 0; a < 4; a++) {
    float4 v = *(const float4*)&ws[offs[a] + n * HWHW + pix0];
    float sc = scales[a];
    v.x *= sc; v.y *= sc; v.z *= sc; v.w *= sc;
    float mx = fmaxf(fmaxf(v.x, v.y), fmaxf(v.z, v.w));
    mx = block_max256(mx, sm);
    float z = expf(v.x - mx) + expf(v.y - mx) + expf(v.z - mx) + expf(v.w - mx);
    z = block_sum256(z, sm);
    if (tid == 0) {
      ws[OFF_MXP + a * 128 + n * 16 + pb] = mx;
      ws[OFF_ZP + a * 128 + n * 16 + pb]  = z;
    }
  }
}

// ---- KC: channel reductions + channel softmax + stats combine. grid 8 x 256
__global__ __launch_bounds__(256) void kC_stats2(float* __restrict__ ws) {
  int tid = threadIdx.x, n = blockIdx.x;
  __shared__ float sm[4];

  float chS = 0.f, chT = 0.f, Dv = 0.f;
  int base = (n * CC + tid) * 64;
#pragma unroll 4
  for (int k = 0; k < 64; k += 4) {
    float4 a = *(const float4*)&ws[OFF_PCHS + base + k];
    float4 b = *(const float4*)&ws[OFF_PCHT + base + k];
    float4 d = *(const float4*)&ws[OFF_PD + base + k];
    chS += (a.x + a.y) + (a.z + a.w);
    chT += (b.x + b.y) + (b.z + b.w);
    Dv  += (d.x + d.y) + (d.z + d.w);
  }
  ws[OFF_DSUM + n * CC + tid] = Dv;

  float lS = chS * (1.0f / 8192.0f), lT = chT * (1.0f / 8192.0f);
  float mS = block_max256(lS, sm);
  float mT = block_max256(lT, sm);
  float eS = expf(lS - mS), eT = expf(lT - mT);
  float ZS = block_sum256(eS, sm);
  float ZT = block_sum256(eT, sm);
  float cattS = (float)CC * eS / ZS;
  float cattT = (float)CC * eT / ZT;
  ws[OFF_CATT + n * CC + tid] = cattT;
  float mml = block_sum256(fabsf(cattS - cattT), sm);
  if (tid == 0) atomicAdd(&ws[OFF_SCAL + 2], mml);

  if (tid < 4) {
    int a = tid;
    float m = -1e30f;
    for (int i = 0; i < 16; i++)
      m = fmaxf(m, ws[OFF_MXP + a * 128 + n * 16 + i]);
    float Z = 0.f;
    for (int i = 0; i < 16; i++)
      Z += ws[OFF_ZP + a * 128 + n * 16 + i] *
           expf(ws[OFF_MXP + a * 128 + n * 16 + i] - m);
    ws[OFF_STATS + n * 8 + 2 * a]     = m;
    ws[OFF_STATS + n * 8 + 2 * a + 1] = Z;
  }
}

// ---- K4: pass 2. grid (64 pb, 2 cs, 8 n) x 512 thr.
__global__ __launch_bounds__(512, 8) void k4_pass2(
    const float* __restrict__ S, const float* __restrict__ T,
    float* __restrict__ ws) {
  int tid = threadIdx.x;
  int lane = tid & 63, sl = tid >> 6;
  int pb = blockIdx.x, cs = blockIdx.y, n = blockIdx.z;
  int pix0 = pb * 256 + lane * 4;
  int ch0 = cs * 128 + sl * 16;

  __shared__ float l_catt[128];
  __shared__ float wcombL[256], smsL[256], smtL[256];
  __shared__ float l_cs[128], l_ct[128], l_c[8];

  if (tid < 128) l_catt[tid] = ws[OFF_CATT + n * CC + cs * 128 + tid];
  if (tid < 64) {
    float mxFS = ws[OFF_STATS + n * 8 + 0], ZFS = ws[OFF_STATS + n * 8 + 1];
    float mxFT = ws[OFF_STATS + n * 8 + 2], ZFT = ws[OFF_STATS + n * 8 + 3];
    float mxCS = ws[OFF_STATS + n * 8 + 4], ZCS = ws[OFF_STATS + n * 8 + 5];
    float mxCT = ws[OFF_STATS + n * 8 + 6], ZCT = ws[OFF_STATS + n * 8 + 7];
    float bgc  = ws[OFF_BG + n];
    int gp = n * HWHW + pb * 256 + tid * 4;
    float4 fS = *(const float4*)&ws[OFF_FEA_S + gp];
    float4 fT = *(const float4*)&ws[OFF_FEA_T + gp];
    float4 cS = *(const float4*)&ws[OFF_CM_S + gp];
    float4 cT = *(const float4*)&ws[OFF_CM_T + gp];
    float4 mf = *(const float4*)&ws[OFF_MFG + gp];
    float macc = 0.f;
    float fSa[4] = {fS.x, fS.y, fS.z, fS.w};
    float fTa[4] = {fT.x, fT.y, fT.z, fT.w};
    float cSa[4] = {cS.x, cS.y, cS.z, cS.w};
    float cTa[4] = {cT.x, cT.y, cT.z, cT.w};
    float mfa[4] = {mf.x, mf.y, mf.z, mf.w};
#pragma unroll
    for (int j = 0; j < 4; j++) {
      float pT = expf(fTa[j] * (1.0f / 128.0f) - mxFT) / ZFT;
      float pS = expf(fSa[j] * (1.0f / 128.0f) - mxFS) / ZFS;
      float Satt = (float)HWHW * pT;
      float mbg = (mfa[j] > 0.f) ? 0.f : ((bgc > 0.f) ? 1.0f / bgc : 1.0f);
      wcombL[tid * 4 + j] = Satt * (C_ALPHA * mfa[j] + C_BETA * mbg);
      smsL[tid * 4 + j] = expf(cSa[j] - mxCS) / ZCS;
      smtL[tid * 4 + j] = expf(cTa[j] - mxCT) / ZCT;
      macc += fabsf(pS - pT);
    }
    macc = dpp_wave_sum(macc);
    if (tid == 63 && cs == 0) atomicAdd(&ws[OFF_SCAL + 2], macc * (float)HWHW);
  }
  __syncthreads();

  float4 sms = *(const float4*)&smsL[lane * 4];
  float4 smt = *(const float4*)&smtL[lane * 4];
  float4 wcb = *(const float4*)&wcombL[lane * 4];

  const float* baseS = S + (size_t)(n * CC + ch0) * HWHW + pix0;
  const float* baseT = T + (size_t)(n * CC + ch0) * HWHW + pix0;

  float awx = 0, awy = 0, awz = 0, aww = 0;
#pragma unroll 2
  for (int c = 0; c < 16; c++) {
    float4 s4 = *(const float4*)(baseS + (size_t)c * HWHW);
    float4 t4 = *(const float4*)(baseT + (size_t)c * HWHW);
    float ca = l_catt[sl * 16 + c];
    float dx = s4.x - t4.x, dy = s4.y - t4.y, dz = s4.z - t4.z, dw = s4.w - t4.w;
    awx = fmaf(dx * dx, ca, awx); awy = fmaf(dy * dy, ca, awy);
    awz = fmaf(dz * dz, ca, awz); aww = fmaf(dw * dw, ca, aww);
    float xs = fmaf(s4.x, sms.x, fmaf(s4.y, sms.y, fmaf(s4.z, sms.z, s4.w * sms.w)));
    float xt = fmaf(t4.x, smt.x, fmaf(t4.y, smt.y, fmaf(t4.z, smt.z, t4.w * smt.w)));
    xs = dpp_wave_sum(xs);
    xt = dpp_wave_sum(xt);
    if (lane == 63) { l_cs[sl * 16 + c] = xs; l_ct[sl * 16 + c] = xt; }
  }

  float contrib = fmaf(awx, wcb.x, fmaf(awy, wcb.y, fmaf(awz, wcb.z, aww * wcb.w)));
  contrib = dpp_wave_sum(contrib);
  if (lane == 63) l_c[sl] = contrib;
  __syncthreads();

  if (tid < 128) {
    int bo = (n * CC + cs * 128 + tid) * 64 + pb;
    ws[OFF_PCTXS + bo] = l_cs[tid];
    ws[OFF_PCTXT + bo] = l_ct[tid];
  }
  if (tid == 0) {
    float t = 0.f;
#pragma unroll
    for (int i = 0; i < 8; i++) t += l_c[i];
    atomicAdd(&ws[OFF_SCAL + 1], t);
  }
}

// ---- K4b: reduce ctx partials. grid 8 x 256
__global__ __launch_bounds__(256) void k4b_ctxreduce(float* __restrict__ ws) {
  int tid = threadIdx.x, n = blockIdx.x;
  float a = 0.f, b = 0.f;
  int base = (n * CC + tid) * 64;
#pragma unroll 4
  for (int k = 0; k < 64; k += 4) {
    float4 x = *(const float4*)&ws[OFF_PCTXS + base + k];
    float4 y = *(const float4*)&ws[OFF_PCTXT + base + k];
    a += (x.x + x.y) + (x.z + x.w);
    b += (y.x + y.y) + (y.z + y.w);
  }
  ws[OFF_CTXS + n * CC + tid] = a;
  ws[OFF_CTXT + n * CC + tid] = b;
}

// ---- K5a: GEMM1 + LN + ReLU. grid 16 (n*2+st) x 128 thr; thread = hidden j
__global__ __launch_bounds__(128) void k5a_mlp1(
    const float* __restrict__ w1_s, const float* __restrict__ b1_s,
    const float* __restrict__ g_s,  const float* __restrict__ be_s,
    const float* __restrict__ w1_t, const float* __restrict__ b1_t,
    const float* __restrict__ g_t,  const float* __restrict__ be_t,
    float* __restrict__ ws) {
  int tid = threadIdx.x;
  int n = blockIdx.x >> 1, st = blockIdx.x & 1;
  const float* w1 = st ? w1_t : w1_s;
  const float* b1 = st ? b1_t : b1_s;
  const float* g  = st ? g_t  : g_s;
  const float* be = st ? be_t : be_s;
  int ctxoff = (st ? OFF_CTXT : OFF_CTXS) + n * CC;

  __shared__ float ctx[CC];
  __shared__ float red[2];
  ctx[tid]       = ws[ctxoff + tid];
  ctx[tid + 128] = ws[ctxoff + tid + 128];
  __syncthreads();

  float acc = b1[tid];
  const float* wr = w1 + tid * CC;
#pragma unroll 8
  for (int c = 0; c < CC; c += 4) {
    float4 w = *(const float4*)(wr + c);
    acc = fmaf(w.x, ctx[c], acc);
    acc = fmaf(w.y, ctx[c + 1], acc);
    acc = fmaf(w.z, ctx[c + 2], acc);
    acc = fmaf(w.w, ctx[c + 3], acc);
  }

  // LN over 128 threads (2 waves)
  float v = dpp_wave_sum(acc);
  if ((tid & 63) == 63) red[tid >> 6] = v;
  __syncthreads();
  float mean = (red[0] + red[1]) * (1.0f / 128.0f);
  __syncthreads();
  float dm = acc - mean;
  v = dpp_wave_sum(dm * dm);
  if ((tid & 63) == 63) red[tid >> 6] = v;
  __syncthreads();
  float var = (red[0] + red[1]) * (1.0f / 128.0f);
  float q = dm * (1.0f / sqrtf(var + C_LN_EPS)) * g[tid] + be[tid];
  ws[OFF_Y + blockIdx.x * 128 + tid] = q > 0.f ? q : 0.f;
}

// ---- K5b: GEMM2 + rela cross terms. grid 8 (n) x 256 thr; thread = out channel c
__global__ __launch_bounds__(256) void k5b_mlp2(
    const float* __restrict__ w2_s, const float* __restrict__ b2_s,
    const float* __restrict__ w2_t, const float* __restrict__ b2_t,
    float* __restrict__ ws) {
  int tid = threadIdx.x, n = blockIdx.x;
  __shared__ float ysh[128], yth[128];
  __shared__ float sm[4];
  if (tid < 128) ysh[tid] = ws[OFF_Y + (n * 2 + 0) * 128 + tid];
  else           yth[tid - 128] = ws[OFF_Y + (n * 2 + 1) * 128 + (tid - 128)];
  __syncthreads();

  float es = b2_s[tid], et = b2_t[tid];
  const float* w2sr = w2_s + tid * 128;
  const float* w2tr = w2_t + tid * 128;
#pragma unroll 8
  for (int j = 0; j < 128; j += 4) {
    float4 a = *(const float4*)(w2sr + j);
    float4 b = *(const float4*)(w2tr + j);
    es = fmaf(a.x, ysh[j], es); es = fmaf(a.y, ysh[j + 1], es);
    es = fmaf(a.z, ysh[j + 2], es); es = fmaf(a.w, ysh[j + 3], es);
    et = fmaf(b.x, yth[j], et); et = fmaf(b.y, yth[j + 1], et);
    et = fmaf(b.z, yth[j + 2], et); et = fmaf(b.w, yth[j + 3], et);
  }
  float e = es - et;
  float rp = 2.0f * e * ws[OFF_DSUM + n * CC + tid] + (float)HWHW * e * e;
  rp = block_sum256(rp, sm);
  if (tid == 0) ws[OFF_RELAP + n] = rp;
}

// ---- K5c: final combine. 1 block x 64
__global__ __launch_bounds__(64) void k5c_final(float* __restrict__ ws,
                                                float* __restrict__ out) {
  int lane = threadIdx.x;
  float r = (lane < NN) ? ws[OFF_RELAP + lane] : 0.f;
  r = dpp_wave_sum(r);
  if (lane == 63) {
    float rela = ws[OFF_SCAL + 0] + r;
    out[0] = (ws[OFF_SCAL + 1] + C_GAMMA * ws[OFF_SCAL + 2] + C_LAMB * rela) *
             (1.0f / (float)NN);
  }
}

extern "C" void kernel_launch(void* const* d_in, const int* in_sizes, int n_in,
                              void* d_out, int out_size, void* d_ws, size_t ws_size,
                              hipStream_t stream) {
  const float* S    = (const float*)d_in[0];
  const float* T    = (const float*)d_in[1];
  const float* gt   = (const float*)d_in[2];
  const float* w_ms = (const float*)d_in[3];
  const float* w_mt = (const float*)d_in[5];
  const float* w1_s = (const float*)d_in[7];
  const float* b1_s = (const float*)d_in[8];
  const float* g_s  = (const float*)d_in[9];
  const float* be_s = (const float*)d_in[10];
  const float* w2_s = (const float*)d_in[11];
  const float* b2_s = (const float*)d_in[12];
  const float* w1_t = (const float*)d_in[13];
  const float* b1_t = (const float*)d_in[14];
  const float* g_t  = (const float*)d_in[15];
  const float* be_t = (const float*)d_in[16];
  const float* w2_t = (const float*)d_in[17];
  const float* b2_t = (const float*)d_in[18];
  float* ws = (float*)d_ws;
  float* out = (float*)d_out;

  // zero per-pixel accumulation arrays (FEA_S..CM_T) + BG/SCAL scalars
  hipMemsetAsync(ws, 0, 524288 * sizeof(float), stream);
  hipMemsetAsync(ws + OFF_BG, 0, 16 * sizeof(float), stream);

  k1_pass1<<<dim3(64, 2, 8), dim3(512), 0, stream>>>(S, T, w_ms, w_mt, ws);
  k2_mask<<<dim3(512), dim3(256), 0, stream>>>(gt, ws);
  kB_stats1<<<dim3(16, 8), dim3(256), 0, stream>>>(ws);
  kC_stats2<<<dim3(8), dim3(256), 0, stream>>>(ws);
  k4_pass2<<<dim3(64, 2, 8), dim3(512), 0, stream>>>(S, T, ws);
  k4b_ctxreduce<<<dim3(8), dim3(256), 0, stream>>>(ws);
  k5a_mlp1<<<dim3(16), dim3(128), 0, stream>>>(w1_s, b1_s, g_s, be_s,
                                               w1_t, b1_t, g_t, be_t, ws);
  k5b_mlp2<<<dim3(8), dim3(256), 0, stream>>>(w2_s, b2_s, w2_t, b2_t, ws);
  k5c_final<<<dim3(1), dim3(64), 0, stream>>>(ws, out);
}